// Round 16
// baseline (235.772 us; speedup 1.0000x reference)
//
#include <hip/hip_runtime.h>
#include <hip/hip_bf16.h>
#include <cstdint>

// MHD PINN loss, SINGLE fused kernel (prep dispatch eliminated), persistent,
// 2-phase balanced pipeline (R15 structure: device 170.4us, harness 215.3us).
// R16 change (single variable vs R15): prep_weights dispatch + workspace GONE.
// In-kernel weight transpose via LDS-STAGED cooperative loads (the spill-safe
// version of R13's failed attempt): each 4-wave group stages 32 rows x 256 cols
// of its fp32 W into scratch LDS (G2->XsA, G3->XsB[0]; both dead pre-main-loop),
// coalesced float4 loads; post-barrier each lane extracts 8 col-elements + f2b
// -> wf. Transient regs only (R13 spilled by doing per-lane strided fp32 loads
// against the live wf build-up). 8 chunks x 2 barriers, one-time, W2/W3 are
// L2/L3-resident. Removes: 1 dispatch + launch gap + memset-adjacent overhead
// (the 45us harness-device gap, stable across R8/R10/R15).
// R15 keeps: T5 setprio around MFMA clusters; bias folded into MFMA C-in.
// Falsified-levers ledger (do not retry): 2 blocks/CU (R3), L1-in-K-loop +
// L4-reg-fusion (R4/R6/R7 spill), anti-phased K-loops (R9), LDS swizzle (R11),
// 16-wave (R12), per-lane fp32 transposed prologue loads (R13 spill).
// Noise floor: +/-6% device (R10 174.2 vs R14 185.2, same binary).
// Per iteration (TWO barriers):
//   P1 (MFMA): G2 = L2(i): XsA -> XsB[i&1] ; G3 = L3(i-1): XsB[(i-1)&1] -> XsC.
//   P2 (rest): G2 = L1(i+1) -> XsA ; G3 = L4(i-1) MFMA: XsC -> Y4[(i-1)&1] ;
//              G3-wave4 lanes0-15 += residual(i-2); G3-wave7 = cs prefetch(i+2).
// Streams: s=0 fwd h, s=1..3 tangents d/dx,d/dy,d/dt; X row = s*16+p, col = neuron.

#define LDW 264   // X tile row stride in ushorts (2-way bank max on b128 reads)
#define TPTS 16
#define GRIDB 256

typedef __attribute__((ext_vector_type(8))) short v8h;   // 8 x bf16
typedef __attribute__((ext_vector_type(4))) float v4f;

__device__ __forceinline__ ushort f2b(float f) {           // fp32 -> bf16 RNE
    uint32_t u = __float_as_uint(f);
    u = (u + 0x7fffu + ((u >> 16) & 1u)) >> 16;
    return (ushort)u;
}
__device__ __forceinline__ uint32_t pk2(float a, float b) { // v_cvt_pk_bf16_f32
    union { __hip_bfloat162 h2; uint32_t u; } cv;
    cv.h2 = __float22bfloat162_rn(make_float2(a, b));
    return cv.u;
}
__device__ __forceinline__ float fast_tanh(float x) {
    float e = __expf(2.0f * x);
    return 1.0f - 2.0f * __builtin_amdgcn_rcpf(e + 1.0f);
}

// one L1 point: 2 adjacent neurons (jj0, jj0+1), packed uint writes
__device__ __forceinline__ void l1_point(ushort* __restrict__ Xd, const float* __restrict__ csb,
                                         int p, int jj0,
                                         float w0a, float w1a, float w2a, float ba,
                                         float w0b, float w1b, float w2b, float bb_) {
    float x = csb[p * 3], yc = csb[p * 3 + 1], tc = csb[p * 3 + 2];
    float pA = fmaf(x, w0a, fmaf(yc, w1a, fmaf(tc, w2a, ba)));
    float pB = fmaf(x, w0b, fmaf(yc, w1b, fmaf(tc, w2b, bb_)));
    float hA = fast_tanh(pA), hB = fast_tanh(pB);
    float dA = 1.0f - hA * hA, dB = 1.0f - hB * hB;
    *(uint32_t*)(&Xd[p * LDW + jj0])        = pk2(hA, hB);
    *(uint32_t*)(&Xd[(16 + p) * LDW + jj0]) = pk2(dA * w0a, dB * w0b);
    *(uint32_t*)(&Xd[(32 + p) * LDW + jj0]) = pk2(dA * w1a, dB * w1b);
    *(uint32_t*)(&Xd[(48 + p) * LDW + jj0]) = pk2(dA * w2a, dB * w2b);
}

// hidden layer: D = W(64x256 slice in regs) * src^T(256x64); epilogue -> dst (bf16)
// K-loop: nt-outer, rolling 3-deep B prefetch. Bias pre-loaded into C-in (nt=0).
__device__ __forceinline__ void dense_layer(const ushort* __restrict__ src,
                                            ushort* __restrict__ dst,
                                            const v8h (*wf)[8],
                                            const float* __restrict__ biasp,
                                            int wvg, int q, int l15) {
    v4f acc[4][4];
    #pragma unroll
    for (int a = 0; a < 4; a++) {
        // fwd stream (nt=0): C-in = bias (row = neuron); JVP streams: zero.
        acc[a][0] = *(const v4f*)(&biasp[wvg * 64 + a * 16 + q * 4]);
        #pragma unroll
        for (int b = 1; b < 4; b++) {
            v4f z = {0.0f, 0.0f, 0.0f, 0.0f};
            acc[a][b] = z;
        }
    }
    __builtin_amdgcn_s_setprio(1);
    #pragma unroll
    for (int nt = 0; nt < 4; nt++) {
        const ushort* cb = &src[(nt * 16 + l15) * LDW + q * 8];
        v8h B[3];
        B[0] = *(const v8h*)(cb);
        B[1] = *(const v8h*)(cb + 32);
        #pragma unroll
        for (int kk = 0; kk < 8; kk++) {
            if (kk < 6)
                B[(kk + 2) % 3] = *(const v8h*)(cb + (kk + 2) * 32);   // 2-ahead prefetch
            const v8h Bc = B[kk % 3];
            #pragma unroll
            for (int mt = 0; mt < 4; mt++)
                acc[mt][nt] = __builtin_amdgcn_mfma_f32_16x16x32_bf16(
                                  wf[mt][kk], Bc, acc[mt][nt], 0, 0, 0);
        }
    }
    __builtin_amdgcn_s_setprio(0);
    // D row(neuron) = mt*16 + q*4 + r, col = nt*16 + l15 (stream = nt, point = l15)
    #pragma unroll
    for (int mt = 0; mt < 4; mt++) {
        const int nb = wvg * 64 + mt * 16 + q * 4;
        float h0 = fast_tanh(acc[mt][0][0]);
        float h1 = fast_tanh(acc[mt][0][1]);
        float h2 = fast_tanh(acc[mt][0][2]);
        float h3 = fast_tanh(acc[mt][0][3]);
        float d0 = 1.0f - h0 * h0, d1 = 1.0f - h1 * h1;
        float d2 = 1.0f - h2 * h2, d3 = 1.0f - h3 * h3;
        uint2 w;
        w.x = pk2(h0, h1); w.y = pk2(h2, h3);
        *(uint2*)(&dst[l15 * LDW + nb]) = w;
        #pragma unroll
        for (int s = 1; s < 4; s++) {
            w.x = pk2(d0 * acc[mt][s][0], d1 * acc[mt][s][1]);
            w.y = pk2(d2 * acc[mt][s][2], d3 * acc[mt][s][3]);
            *(uint2*)(&dst[(s * 16 + l15) * LDW + nb]) = w;
        }
    }
}

__global__ __launch_bounds__(512, 2)
void mhd_fused(const float* __restrict__ coords,
               const float* __restrict__ W1, const float* __restrict__ b1,
               const float* __restrict__ W2, const float* __restrict__ b2,
               const float* __restrict__ W3, const float* __restrict__ b3,
               const float* __restrict__ W4, const float* __restrict__ b4,
               const float* __restrict__ wts,
               float* __restrict__ out, int npts, float inv_n) {
    __shared__ ushort XsA[64 * LDW];        // L1 out; PROLOGUE: G2 transpose scratch
    __shared__ ushort XsB[2][64 * LDW];     // L2 out (dbuf); PROLOGUE: XsB[0] = G3 scratch
    __shared__ ushort XsC[64 * LDW];        // L3 out (single)
    __shared__ ushort W4s[16 * LDW];        // W4^T padded, bf16
    __shared__ float  bias_s[512];          // [0:256)=b2, [256:512)=b3
    __shared__ float  cs[2][TPTS * 3];      // coords (dbuf, 2 tiles ahead)
    __shared__ float  Y4[2][4][TPTS][8];    // [tile&1][stream][point][row]

    const int tid  = threadIdx.x;
    const int lane = tid & 63;
    const int wv   = tid >> 6;      // 0..7
    const int q    = lane >> 4;
    const int l15  = lane & 15;
    const int g3   = wv >> 2;       // 0 = G2 (L1+L2), 1 = G3 (L3+L4+residual+cs)
    const int wvg  = wv & 3;
    const int gtid = tid & 255;     // thread index within 4-wave group

    // ---- stage W4s (transposed from raw fp32 W4, padded) + biases -------------
    for (int idx = tid; idx < 16 * 256; idx += 512) {
        int r = idx >> 8, c = idx & 255;            // r = output j (pad>=6), c = neuron
        W4s[r * LDW + c] = (r < 6) ? f2b(W4[c * 6 + r]) : (ushort)0;
    }
    bias_s[tid] = (tid < 256) ? b2[tid] : b3[tid - 256];

    // ---- in-kernel weight transpose via LDS staging (replaces prep dispatch) --
    // Group g loads its fp32 W in 8 chunks of 32 rows x 256 cols (32KB) into its
    // scratch (G2: XsA, G3: XsB[0]); after barrier each lane extracts 8 column-
    // elements per (mt,kk) and packs wf. Transient registers only.
    const float* Wraw = g3 ? W3 : W2;
    float* stageF = (float*)(g3 ? (void*)XsB[0] : (void*)XsA);
    v8h wf[4][8];                                   // 128 regs (built progressively)
    for (int kk = 0; kk < 8; kk++) {
        // cooperative coalesced load: 8192 floats with 256 threads (8x float4)
        #pragma unroll
        for (int t = 0; t < 8; t++) {
            const int idx = gtid * 4 + t * 1024;
            *(v4f*)(&stageF[idx]) = *(const v4f*)(&Wraw[kk * 32 * 256 + idx]);
        }
        __syncthreads();   // chunk staged (both groups)
        #pragma unroll
        for (int mt = 0; mt < 4; mt++) {
            const int n = wvg * 64 + mt * 16 + l15;
            v8h v;
            #pragma unroll
            for (int j = 0; j < 8; j++)
                v[j] = (short)f2b(stageF[(q * 8 + j) * 256 + n]);
            wf[mt][kk] = v;
        }
        __syncthreads();   // extracts done; scratch free for next chunk
    }

    // ---- L1 constants: G2 only (2 adjacent neurons / thread) ------------------
    const int jj0 = (tid & 127) * 2, half8 = (tid >> 7) * 8;
    float w0a = 0, w1a = 0, w2a = 0, ba = 0, w0b = 0, w1b = 0, w2b = 0, bb_ = 0;
    if (!g3) {
        w0a = W1[jj0];       w1a = W1[256 + jj0];     w2a = W1[512 + jj0];     ba  = b1[jj0];
        w0b = W1[jj0 + 1];   w1b = W1[256 + jj0 + 1]; w2b = W1[512 + jj0 + 1]; bb_ = b1[jj0 + 1];
    }

    const float b40 = b4[0], b41 = b4[1], b42 = b4[2], b43 = b4[3], b44 = b4[4], b45 = b4[5];
    const float wt0 = wts[0], wt1 = wts[1], wt2_ = wts[2], wt3_ = wts[3],
                wt4_ = wts[4], wt5 = wts[5], wt6 = wts[6];

    const int ntiles = (npts + TPTS - 1) / TPTS;
    const int nt_blk = (ntiles > (int)blockIdx.x)
                         ? (ntiles - (int)blockIdx.x + GRIDB - 1) / GRIDB : 0;
    float vsum = 0.0f;

    // ---- prologue: cs(0), cs(1); then L1(0) -> XsA ----------------------------
    if (tid < 96) {
        int b = tid / 48, r = tid % 48;
        if (b < nt_blk) {
            int p = r / 3, c = r % 3;
            int gp = ((int)blockIdx.x + b * GRIDB) * TPTS + p;
            if (gp >= npts) gp = npts - 1;
            cs[b][r] = coords[gp * 3 + c];
        }
    }
    __syncthreads();   // cs ready; scratch areas now become pipeline buffers
    if (!g3 && nt_blk > 0) {
        #pragma unroll
        for (int pp = 0; pp < 8; pp++)
            l1_point(XsA, cs[0], half8 + pp, jj0, w0a, w1a, w2a, ba, w0b, w1b, w2b, bb_);
    }
    __syncthreads();

    // ---- main loop: 2 barriers per iteration ----------------------------------
    for (int i = 0; i <= nt_blk + 1; ++i) {
        // ================= P1: MFMA phase (both groups K-loop together) =========
        if (!g3) {
            if (i < nt_blk)
                dense_layer(XsA, XsB[i & 1], wf, bias_s, wvg, q, l15);         // L2(i)
        } else {
            if (i >= 1 && i <= nt_blk)
                dense_layer(XsB[(i + 1) & 1], XsC, wf, bias_s + 256, wvg, q, l15); // L3(i-1)
        }
        __syncthreads();   // B1: XsB(i)/XsC(i-1) ready; XsA free for L1(i+1)

        // ================= P2: L1 / L4 / residual / cs =================
        if (!g3) {
            if (i + 1 < nt_blk) {          // L1(tile i+1) -> XsA
                const float* csb = cs[(i + 1) & 1];
                #pragma unroll
                for (int pp = 0; pp < 8; pp++)
                    l1_point(XsA, csb, half8 + pp, jj0,
                             w0a, w1a, w2a, ba, w0b, w1b, w2b, bb_);
            }
        } else {
            // -- L4 (tile i-1): wave wvg handles stream wvg --
            if (i >= 1 && i <= nt_blk) {
                v4f a4 = {0.0f, 0.0f, 0.0f, 0.0f};
                __builtin_amdgcn_s_setprio(1);
                #pragma unroll
                for (int kk = 0; kk < 8; kk++) {
                    v8h A  = *(const v8h*)(&W4s[l15 * LDW + kk * 32 + q * 8]);
                    v8h Bf = *(const v8h*)(&XsC[(wvg * 16 + l15) * LDW + kk * 32 + q * 8]);
                    a4 = __builtin_amdgcn_mfma_f32_16x16x32_bf16(A, Bf, a4, 0, 0, 0);
                }
                __builtin_amdgcn_s_setprio(0);
                if (q < 2) {
                    #pragma unroll
                    for (int r = 0; r < 4; r++)
                        Y4[(i + 1) & 1][wvg][l15][q * 4 + r] = a4[r];   // (i-1)&1
                }
            }
            // -- residuals for tile i-2 (wave 4, lanes 0..15; pointer form) --
            if (wv == 4 && lane < 16 && i >= 2) {
                const int pb = ((int)blockIdx.x + (i - 2) * GRIDB) * TPTS;
                if (pb + lane < npts) {
                    const int ib = i & 1;   // (i-2)&1
                    const float* Yh = Y4[ib][0][lane];
                    const float* JX = Y4[ib][1][lane];
                    const float* JY = Y4[ib][2][lane];
                    const float* JT = Y4[ib][3][lane];
                    const float g1 = 1.5f;
                    float rho = Yh[0] + b40, vx = Yh[1] + b41, vy = Yh[2] + b42;
                    float Bx  = Yh[3] + b43, By = Yh[4] + b44, P  = Yh[5] + b45;
                    float v2 = vx * vx + vy * vy;
                    float dt_rho = JT[0];
                    float dt_rhovx = dt_rho * vx + rho * JT[1];
                    float dt_rhovy = dt_rho * vy + rho * JT[2];
                    auto dE = [&](const float* J) {
                        return J[5] * g1 + 0.5f * J[0] * v2 + rho * (vx * J[1] + vy * J[2]) + Bx * J[3] + By * J[4];
                    };
                    float dE_dx = dE(JX), dE_dy = dE(JY), dE_dt = dE(JT);
                    float div_v = JX[1] + JY[2];
                    float div_B = JX[3] + JY[4];
                    float continuity = dt_rho + rho * div_v;
                    float dPm_dx = JX[5] + Bx * JX[3] + By * JX[4];
                    float dPm_dy = JY[5] + Bx * JY[3] + By * JY[4];
                    float momentum_x = dt_rhovx + dPm_dx - (Bx * JX[3] + By * JY[3]);
                    float momentum_y = dt_rhovy + dPm_dy - (Bx * JX[4] + By * JY[4]);
                    auto dG = [&](const float* J) {
                        return J[1] * By + vx * J[4] - J[2] * Bx - vy * J[3];
                    };
                    float induction_x = JT[3] + dG(JY);
                    float induction_y = JT[4] - dG(JX);
                    float E = P * g1 + 0.5f * rho * v2 + 0.5f * (Bx * Bx + By * By);
                    float S = E + P + 0.5f * (Bx * Bx + By * By);
                    float dS_dx = dE_dx + JX[5] + Bx * JX[3] + By * JX[4];
                    float dS_dy = dE_dy + JY[5] + Bx * JY[3] + By * JY[4];
                    float D = Bx * vx + By * vy;
                    auto dD = [&](const float* J) {
                        return J[3] * vx + Bx * J[1] + J[4] * vy + By * J[2];
                    };
                    float dFx_dx = dS_dx * vx + S * JX[1] - dD(JX) * Bx - D * JX[3];
                    float dFy_dy = dS_dy * vy + S * JY[2] - dD(JY) * By - D * JY[4];
                    float energy = dE_dt + dFx_dx + dFy_dy;
                    vsum += wt0 * continuity * continuity
                          + wt1 * momentum_x * momentum_x
                          + wt2_ * momentum_y * momentum_y
                          + wt3_ * induction_x * induction_x
                          + wt4_ * induction_y * induction_y
                          + wt5 * energy * energy
                          + wt6 * div_B * div_B;
                }
            }
            // -- cs prefetch for tile i+2 (wave 7, lanes 0..47) --
            if (wv == 7 && lane < 48 && (i + 2) < nt_blk) {
                int p = lane / 3, c = lane % 3;
                int gp = ((int)blockIdx.x + (i + 2) * GRIDB) * TPTS + p;
                if (gp >= npts) gp = npts - 1;
                cs[i & 1][lane] = coords[gp * 3 + c];   // (i+2)&1 == i&1
            }
        }
        __syncthreads();   // B2: XsA(i+1), Y4(i-1), cs(i+2) ready
    }

    if (wv == 4) {
        #pragma unroll
        for (int off = 8; off >= 1; off >>= 1)
            vsum += __shfl_down(vsum, off, 64);
        if (lane == 0) atomicAdd(out, vsum * inv_n);
    }
}

extern "C" void kernel_launch(void* const* d_in, const int* in_sizes, int n_in,
                              void* d_out, int out_size, void* d_ws, size_t ws_size,
                              hipStream_t stream) {
    const float* coords = (const float*)d_in[0];
    const float* W1 = (const float*)d_in[1];
    const float* b1 = (const float*)d_in[2];
    const float* W2 = (const float*)d_in[3];
    const float* b2 = (const float*)d_in[4];
    const float* W3 = (const float*)d_in[5];
    const float* b3 = (const float*)d_in[6];
    const float* W4 = (const float*)d_in[7];
    const float* b4 = (const float*)d_in[8];
    const float* wts = (const float*)d_in[9];
    const int npts = in_sizes[0] / 3;

    hipMemsetAsync(d_out, 0, sizeof(float), stream);
    mhd_fused<<<GRIDB, 512, 0, stream>>>(coords, W1, b1, W2, b2, W3, b3, W4, b4, wts,
                                         (float*)d_out, npts, 1.0f / npts);
}

// Round 17
// 234.705 us; speedup vs baseline: 1.0045x; 1.0045x over previous
//
#include <hip/hip_runtime.h>
#include <hip/hip_bf16.h>
#include <cstdint>

// MHD PINN loss, SINGLE fused kernel (prep dispatch eliminated), persistent,
// 2-phase balanced pipeline (R15 structure: device 170.4us, harness 215.3us).
// R17 = R16 + ONE-LINE FIX: #pragma unroll on the weight-transpose chunk loop.
// R16's 39.8MB scratch was rule #20 (runtime-indexed ext_vector array): the
// un-unrolled `for(kk)` made wf[mt][kk] runtime-indexed -> compiler allocated
// all 128 wf regs in LOCAL MEMORY; every main-loop MFMA read its A-operand from
// scratch. Unrolling makes every wf index compile-time -> registers.
// In-kernel transpose (spill-safe design, now correctly indexed): each 4-wave
// group stages 32x256 fp32 rows of its W into dead-at-prologue LDS (G2->XsA,
// G3->XsB[0]) with coalesced float4 loads; post-barrier each lane extracts its
// 8 column-elements + f2b -> wf. 8 chunks x 2 barriers, one-time, L2/L3-served.
// R15 keeps: T5 setprio around MFMA clusters; bias folded into MFMA C-in.
// Falsified-levers ledger (do not retry): 2 blocks/CU (R3), L1-in-K-loop +
// L4-reg-fusion (R4/R6/R7 spill), anti-phased K-loops (R9), LDS swizzle (R11),
// 16-wave (R12), per-lane fp32 transposed prologue loads (R13 spill),
// un-unrolled progressive wf build (R16, rule #20).
// Noise floor: +/-6% device (R10 174.2 vs R14 185.2, same binary).
// Per iteration (TWO barriers):
//   P1 (MFMA): G2 = L2(i): XsA -> XsB[i&1] ; G3 = L3(i-1): XsB[(i-1)&1] -> XsC.
//   P2 (rest): G2 = L1(i+1) -> XsA ; G3 = L4(i-1) MFMA: XsC -> Y4[(i-1)&1] ;
//              G3-wave4 lanes0-15 += residual(i-2); G3-wave7 = cs prefetch(i+2).
// Streams: s=0 fwd h, s=1..3 tangents d/dx,d/dy,d/dt; X row = s*16+p, col = neuron.

#define LDW 264   // X tile row stride in ushorts (2-way bank max on b128 reads)
#define TPTS 16
#define GRIDB 256

typedef __attribute__((ext_vector_type(8))) short v8h;   // 8 x bf16
typedef __attribute__((ext_vector_type(4))) float v4f;

__device__ __forceinline__ ushort f2b(float f) {           // fp32 -> bf16 RNE
    uint32_t u = __float_as_uint(f);
    u = (u + 0x7fffu + ((u >> 16) & 1u)) >> 16;
    return (ushort)u;
}
__device__ __forceinline__ uint32_t pk2(float a, float b) { // v_cvt_pk_bf16_f32
    union { __hip_bfloat162 h2; uint32_t u; } cv;
    cv.h2 = __float22bfloat162_rn(make_float2(a, b));
    return cv.u;
}
__device__ __forceinline__ float fast_tanh(float x) {
    float e = __expf(2.0f * x);
    return 1.0f - 2.0f * __builtin_amdgcn_rcpf(e + 1.0f);
}

// one L1 point: 2 adjacent neurons (jj0, jj0+1), packed uint writes
__device__ __forceinline__ void l1_point(ushort* __restrict__ Xd, const float* __restrict__ csb,
                                         int p, int jj0,
                                         float w0a, float w1a, float w2a, float ba,
                                         float w0b, float w1b, float w2b, float bb_) {
    float x = csb[p * 3], yc = csb[p * 3 + 1], tc = csb[p * 3 + 2];
    float pA = fmaf(x, w0a, fmaf(yc, w1a, fmaf(tc, w2a, ba)));
    float pB = fmaf(x, w0b, fmaf(yc, w1b, fmaf(tc, w2b, bb_)));
    float hA = fast_tanh(pA), hB = fast_tanh(pB);
    float dA = 1.0f - hA * hA, dB = 1.0f - hB * hB;
    *(uint32_t*)(&Xd[p * LDW + jj0])        = pk2(hA, hB);
    *(uint32_t*)(&Xd[(16 + p) * LDW + jj0]) = pk2(dA * w0a, dB * w0b);
    *(uint32_t*)(&Xd[(32 + p) * LDW + jj0]) = pk2(dA * w1a, dB * w1b);
    *(uint32_t*)(&Xd[(48 + p) * LDW + jj0]) = pk2(dA * w2a, dB * w2b);
}

// hidden layer: D = W(64x256 slice in regs) * src^T(256x64); epilogue -> dst (bf16)
// K-loop: nt-outer, rolling 3-deep B prefetch. Bias pre-loaded into C-in (nt=0).
__device__ __forceinline__ void dense_layer(const ushort* __restrict__ src,
                                            ushort* __restrict__ dst,
                                            const v8h (*wf)[8],
                                            const float* __restrict__ biasp,
                                            int wvg, int q, int l15) {
    v4f acc[4][4];
    #pragma unroll
    for (int a = 0; a < 4; a++) {
        // fwd stream (nt=0): C-in = bias (row = neuron); JVP streams: zero.
        acc[a][0] = *(const v4f*)(&biasp[wvg * 64 + a * 16 + q * 4]);
        #pragma unroll
        for (int b = 1; b < 4; b++) {
            v4f z = {0.0f, 0.0f, 0.0f, 0.0f};
            acc[a][b] = z;
        }
    }
    __builtin_amdgcn_s_setprio(1);
    #pragma unroll
    for (int nt = 0; nt < 4; nt++) {
        const ushort* cb = &src[(nt * 16 + l15) * LDW + q * 8];
        v8h B[3];
        B[0] = *(const v8h*)(cb);
        B[1] = *(const v8h*)(cb + 32);
        #pragma unroll
        for (int kk = 0; kk < 8; kk++) {
            if (kk < 6)
                B[(kk + 2) % 3] = *(const v8h*)(cb + (kk + 2) * 32);   // 2-ahead prefetch
            const v8h Bc = B[kk % 3];
            #pragma unroll
            for (int mt = 0; mt < 4; mt++)
                acc[mt][nt] = __builtin_amdgcn_mfma_f32_16x16x32_bf16(
                                  wf[mt][kk], Bc, acc[mt][nt], 0, 0, 0);
        }
    }
    __builtin_amdgcn_s_setprio(0);
    // D row(neuron) = mt*16 + q*4 + r, col = nt*16 + l15 (stream = nt, point = l15)
    #pragma unroll
    for (int mt = 0; mt < 4; mt++) {
        const int nb = wvg * 64 + mt * 16 + q * 4;
        float h0 = fast_tanh(acc[mt][0][0]);
        float h1 = fast_tanh(acc[mt][0][1]);
        float h2 = fast_tanh(acc[mt][0][2]);
        float h3 = fast_tanh(acc[mt][0][3]);
        float d0 = 1.0f - h0 * h0, d1 = 1.0f - h1 * h1;
        float d2 = 1.0f - h2 * h2, d3 = 1.0f - h3 * h3;
        uint2 w;
        w.x = pk2(h0, h1); w.y = pk2(h2, h3);
        *(uint2*)(&dst[l15 * LDW + nb]) = w;
        #pragma unroll
        for (int s = 1; s < 4; s++) {
            w.x = pk2(d0 * acc[mt][s][0], d1 * acc[mt][s][1]);
            w.y = pk2(d2 * acc[mt][s][2], d3 * acc[mt][s][3]);
            *(uint2*)(&dst[(s * 16 + l15) * LDW + nb]) = w;
        }
    }
}

__global__ __launch_bounds__(512, 2)
void mhd_fused(const float* __restrict__ coords,
               const float* __restrict__ W1, const float* __restrict__ b1,
               const float* __restrict__ W2, const float* __restrict__ b2,
               const float* __restrict__ W3, const float* __restrict__ b3,
               const float* __restrict__ W4, const float* __restrict__ b4,
               const float* __restrict__ wts,
               float* __restrict__ out, int npts, float inv_n) {
    __shared__ ushort XsA[64 * LDW];        // L1 out; PROLOGUE: G2 transpose scratch
    __shared__ ushort XsB[2][64 * LDW];     // L2 out (dbuf); PROLOGUE: XsB[0] = G3 scratch
    __shared__ ushort XsC[64 * LDW];        // L3 out (single)
    __shared__ ushort W4s[16 * LDW];        // W4^T padded, bf16
    __shared__ float  bias_s[512];          // [0:256)=b2, [256:512)=b3
    __shared__ float  cs[2][TPTS * 3];      // coords (dbuf, 2 tiles ahead)
    __shared__ float  Y4[2][4][TPTS][8];    // [tile&1][stream][point][row]

    const int tid  = threadIdx.x;
    const int lane = tid & 63;
    const int wv   = tid >> 6;      // 0..7
    const int q    = lane >> 4;
    const int l15  = lane & 15;
    const int g3   = wv >> 2;       // 0 = G2 (L1+L2), 1 = G3 (L3+L4+residual+cs)
    const int wvg  = wv & 3;
    const int gtid = tid & 255;     // thread index within 4-wave group

    // ---- stage W4s (transposed from raw fp32 W4, padded) + biases -------------
    for (int idx = tid; idx < 16 * 256; idx += 512) {
        int r = idx >> 8, c = idx & 255;            // r = output j (pad>=6), c = neuron
        W4s[r * LDW + c] = (r < 6) ? f2b(W4[c * 6 + r]) : (ushort)0;
    }
    bias_s[tid] = (tid < 256) ? b2[tid] : b3[tid - 256];

    // ---- in-kernel weight transpose via LDS staging (replaces prep dispatch) --
    // FULLY UNROLLED chunk loop: every wf[mt][kk] index is compile-time constant
    // (rule #20 — R16's runtime kk pushed wf to scratch: 39.8MB WRITE_SIZE).
    const float* Wraw = g3 ? W3 : W2;
    float* stageF = (float*)(g3 ? (void*)XsB[0] : (void*)XsA);
    v8h wf[4][8];                                   // 128 regs (built progressively)
    #pragma unroll
    for (int kk = 0; kk < 8; kk++) {
        // cooperative coalesced load: 8192 floats with 256 threads (8x float4)
        #pragma unroll
        for (int t = 0; t < 8; t++) {
            const int idx = gtid * 4 + t * 1024;
            *(v4f*)(&stageF[idx]) = *(const v4f*)(&Wraw[kk * 32 * 256 + idx]);
        }
        __syncthreads();   // chunk staged (both groups)
        #pragma unroll
        for (int mt = 0; mt < 4; mt++) {
            const int n = wvg * 64 + mt * 16 + l15;
            v8h v;
            #pragma unroll
            for (int j = 0; j < 8; j++)
                v[j] = (short)f2b(stageF[(q * 8 + j) * 256 + n]);
            wf[mt][kk] = v;
        }
        __syncthreads();   // extracts done; scratch free for next chunk
    }

    // ---- L1 constants: G2 only (2 adjacent neurons / thread) ------------------
    const int jj0 = (tid & 127) * 2, half8 = (tid >> 7) * 8;
    float w0a = 0, w1a = 0, w2a = 0, ba = 0, w0b = 0, w1b = 0, w2b = 0, bb_ = 0;
    if (!g3) {
        w0a = W1[jj0];       w1a = W1[256 + jj0];     w2a = W1[512 + jj0];     ba  = b1[jj0];
        w0b = W1[jj0 + 1];   w1b = W1[256 + jj0 + 1]; w2b = W1[512 + jj0 + 1]; bb_ = b1[jj0 + 1];
    }

    const float b40 = b4[0], b41 = b4[1], b42 = b4[2], b43 = b4[3], b44 = b4[4], b45 = b4[5];
    const float wt0 = wts[0], wt1 = wts[1], wt2_ = wts[2], wt3_ = wts[3],
                wt4_ = wts[4], wt5 = wts[5], wt6 = wts[6];

    const int ntiles = (npts + TPTS - 1) / TPTS;
    const int nt_blk = (ntiles > (int)blockIdx.x)
                         ? (ntiles - (int)blockIdx.x + GRIDB - 1) / GRIDB : 0;
    float vsum = 0.0f;

    // ---- prologue: cs(0), cs(1); then L1(0) -> XsA ----------------------------
    if (tid < 96) {
        int b = tid / 48, r = tid % 48;
        if (b < nt_blk) {
            int p = r / 3, c = r % 3;
            int gp = ((int)blockIdx.x + b * GRIDB) * TPTS + p;
            if (gp >= npts) gp = npts - 1;
            cs[b][r] = coords[gp * 3 + c];
        }
    }
    __syncthreads();   // cs ready; scratch areas now become pipeline buffers
    if (!g3 && nt_blk > 0) {
        #pragma unroll
        for (int pp = 0; pp < 8; pp++)
            l1_point(XsA, cs[0], half8 + pp, jj0, w0a, w1a, w2a, ba, w0b, w1b, w2b, bb_);
    }
    __syncthreads();

    // ---- main loop: 2 barriers per iteration ----------------------------------
    for (int i = 0; i <= nt_blk + 1; ++i) {
        // ================= P1: MFMA phase (both groups K-loop together) =========
        if (!g3) {
            if (i < nt_blk)
                dense_layer(XsA, XsB[i & 1], wf, bias_s, wvg, q, l15);         // L2(i)
        } else {
            if (i >= 1 && i <= nt_blk)
                dense_layer(XsB[(i + 1) & 1], XsC, wf, bias_s + 256, wvg, q, l15); // L3(i-1)
        }
        __syncthreads();   // B1: XsB(i)/XsC(i-1) ready; XsA free for L1(i+1)

        // ================= P2: L1 / L4 / residual / cs =================
        if (!g3) {
            if (i + 1 < nt_blk) {          // L1(tile i+1) -> XsA
                const float* csb = cs[(i + 1) & 1];
                #pragma unroll
                for (int pp = 0; pp < 8; pp++)
                    l1_point(XsA, csb, half8 + pp, jj0,
                             w0a, w1a, w2a, ba, w0b, w1b, w2b, bb_);
            }
        } else {
            // -- L4 (tile i-1): wave wvg handles stream wvg --
            if (i >= 1 && i <= nt_blk) {
                v4f a4 = {0.0f, 0.0f, 0.0f, 0.0f};
                __builtin_amdgcn_s_setprio(1);
                #pragma unroll
                for (int kk = 0; kk < 8; kk++) {
                    v8h A  = *(const v8h*)(&W4s[l15 * LDW + kk * 32 + q * 8]);
                    v8h Bf = *(const v8h*)(&XsC[(wvg * 16 + l15) * LDW + kk * 32 + q * 8]);
                    a4 = __builtin_amdgcn_mfma_f32_16x16x32_bf16(A, Bf, a4, 0, 0, 0);
                }
                __builtin_amdgcn_s_setprio(0);
                if (q < 2) {
                    #pragma unroll
                    for (int r = 0; r < 4; r++)
                        Y4[(i + 1) & 1][wvg][l15][q * 4 + r] = a4[r];   // (i-1)&1
                }
            }
            // -- residuals for tile i-2 (wave 4, lanes 0..15; pointer form) --
            if (wv == 4 && lane < 16 && i >= 2) {
                const int pb = ((int)blockIdx.x + (i - 2) * GRIDB) * TPTS;
                if (pb + lane < npts) {
                    const int ib = i & 1;   // (i-2)&1
                    const float* Yh = Y4[ib][0][lane];
                    const float* JX = Y4[ib][1][lane];
                    const float* JY = Y4[ib][2][lane];
                    const float* JT = Y4[ib][3][lane];
                    const float g1 = 1.5f;
                    float rho = Yh[0] + b40, vx = Yh[1] + b41, vy = Yh[2] + b42;
                    float Bx  = Yh[3] + b43, By = Yh[4] + b44, P  = Yh[5] + b45;
                    float v2 = vx * vx + vy * vy;
                    float dt_rho = JT[0];
                    float dt_rhovx = dt_rho * vx + rho * JT[1];
                    float dt_rhovy = dt_rho * vy + rho * JT[2];
                    auto dE = [&](const float* J) {
                        return J[5] * g1 + 0.5f * J[0] * v2 + rho * (vx * J[1] + vy * J[2]) + Bx * J[3] + By * J[4];
                    };
                    float dE_dx = dE(JX), dE_dy = dE(JY), dE_dt = dE(JT);
                    float div_v = JX[1] + JY[2];
                    float div_B = JX[3] + JY[4];
                    float continuity = dt_rho + rho * div_v;
                    float dPm_dx = JX[5] + Bx * JX[3] + By * JX[4];
                    float dPm_dy = JY[5] + Bx * JY[3] + By * JY[4];
                    float momentum_x = dt_rhovx + dPm_dx - (Bx * JX[3] + By * JY[3]);
                    float momentum_y = dt_rhovy + dPm_dy - (Bx * JX[4] + By * JY[4]);
                    auto dG = [&](const float* J) {
                        return J[1] * By + vx * J[4] - J[2] * Bx - vy * J[3];
                    };
                    float induction_x = JT[3] + dG(JY);
                    float induction_y = JT[4] - dG(JX);
                    float E = P * g1 + 0.5f * rho * v2 + 0.5f * (Bx * Bx + By * By);
                    float S = E + P + 0.5f * (Bx * Bx + By * By);
                    float dS_dx = dE_dx + JX[5] + Bx * JX[3] + By * JX[4];
                    float dS_dy = dE_dy + JY[5] + Bx * JY[3] + By * JY[4];
                    float D = Bx * vx + By * vy;
                    auto dD = [&](const float* J) {
                        return J[3] * vx + Bx * J[1] + J[4] * vy + By * J[2];
                    };
                    float dFx_dx = dS_dx * vx + S * JX[1] - dD(JX) * Bx - D * JX[3];
                    float dFy_dy = dS_dy * vy + S * JY[2] - dD(JY) * By - D * JY[4];
                    float energy = dE_dt + dFx_dx + dFy_dy;
                    vsum += wt0 * continuity * continuity
                          + wt1 * momentum_x * momentum_x
                          + wt2_ * momentum_y * momentum_y
                          + wt3_ * induction_x * induction_x
                          + wt4_ * induction_y * induction_y
                          + wt5 * energy * energy
                          + wt6 * div_B * div_B;
                }
            }
            // -- cs prefetch for tile i+2 (wave 7, lanes 0..47) --
            if (wv == 7 && lane < 48 && (i + 2) < nt_blk) {
                int p = lane / 3, c = lane % 3;
                int gp = ((int)blockIdx.x + (i + 2) * GRIDB) * TPTS + p;
                if (gp >= npts) gp = npts - 1;
                cs[i & 1][lane] = coords[gp * 3 + c];   // (i+2)&1 == i&1
            }
        }
        __syncthreads();   // B2: XsA(i+1), Y4(i-1), cs(i+2) ready
    }

    if (wv == 4) {
        #pragma unroll
        for (int off = 8; off >= 1; off >>= 1)
            vsum += __shfl_down(vsum, off, 64);
        if (lane == 0) atomicAdd(out, vsum * inv_n);
    }
}

extern "C" void kernel_launch(void* const* d_in, const int* in_sizes, int n_in,
                              void* d_out, int out_size, void* d_ws, size_t ws_size,
                              hipStream_t stream) {
    const float* coords = (const float*)d_in[0];
    const float* W1 = (const float*)d_in[1];
    const float* b1 = (const float*)d_in[2];
    const float* W2 = (const float*)d_in[3];
    const float* b2 = (const float*)d_in[4];
    const float* W3 = (const float*)d_in[5];
    const float* b3 = (const float*)d_in[6];
    const float* W4 = (const float*)d_in[7];
    const float* b4 = (const float*)d_in[8];
    const float* wts = (const float*)d_in[9];
    const int npts = in_sizes[0] / 3;

    hipMemsetAsync(d_out, 0, sizeof(float), stream);
    mhd_fused<<<GRIDB, 512, 0, stream>>>(coords, W1, b1, W2, b2, W3, b3, W4, b4, wts,
                                         (float*)d_out, npts, 1.0f / npts);
}

// Round 18
// 214.347 us; speedup vs baseline: 1.1000x; 1.0950x over previous
//
#include <hip/hip_runtime.h>
#include <hip/hip_bf16.h>
#include <cstdint>

// MHD PINN loss, fused + persistent, 2-phase balanced pipeline.
// === FINAL KERNEL (R15 verbatim): session best — device 170.4us, harness 215.3us,
// zero spill, absmax 0. R18 executes R17's pre-commitment: the prep-fusion
// family spilled 4x (R13/R16/R17 + R6/R7 variant, all ~40MB scratch signatures);
// revert to R15 permanently. ===
// Structure: block 512 (8 waves), grid 256 (1 block/CU, 2 waves/SIMD).
// Waves 0-3 (G2) hold L2 weights in regs (wf[4][8]=128); waves 4-7 (G3) hold L3.
// Per iteration (TWO barriers):
//   P1 (MFMA): G2 = L2(i): XsA -> XsB[i&1] ; G3 = L3(i-1): XsB[(i-1)&1] -> XsC.
//   P2 (rest): G2 = L1(i+1) -> XsA ; G3 = L4(i-1) MFMA: XsC -> Y4[(i-1)&1] ;
//              G3-wave4 lanes0-15 += residual(i-2); G3-wave7 = cs prefetch(i+2).
// Techniques banked: nt-outer K-loop w/ 3-deep rolling B prefetch (R10);
// T5 s_setprio(1) around MFMA clusters (R15, +5% w/ MfmaUtil 33->36.6);
// bias folded into MFMA C-in, fwd stream only (R15).
// Falsified-levers ledger (do not retry): 2 blocks/CU (R3: reg-residency caps
// 8 waves/CU), L1-in-K-loop + L4-reg-fusion (R4/R6/R7 spill), anti-phased
// K-loops (R9: lone wave exposes lgkm stalls), LDS swizzle (R11: 1.5e7
// conflicts layout-invariant), 16-wave (R12: reuse halved + unified-file
// spill), in-kernel fp32 weight transpose (R13/R16/R17: prologue spill in
// every arrangement). Noise floor: +/-6% device (R10 174.2 vs R14 185.2).
// Structural account: 264 MFMA/SIMD/tile ~= 5.1k cyc floor; measured ~11.9k;
// gap priced by 2-waves/SIMD occupancy forced by 192-unified-reg working set.
// Streams: s=0 fwd h, s=1..3 tangents d/dx,d/dy,d/dt; X row = s*16+p, col = neuron.

#define LDW 264   // X tile row stride in ushorts (2-way bank max on b128 reads)
#define TPTS 16
#define GRIDB 256

typedef __attribute__((ext_vector_type(8))) short v8h;   // 8 x bf16
typedef __attribute__((ext_vector_type(4))) float v4f;

__device__ __forceinline__ ushort f2b(float f) {           // fp32 -> bf16 RNE
    uint32_t u = __float_as_uint(f);
    u = (u + 0x7fffu + ((u >> 16) & 1u)) >> 16;
    return (ushort)u;
}
__device__ __forceinline__ uint32_t pk2(float a, float b) { // v_cvt_pk_bf16_f32
    union { __hip_bfloat162 h2; uint32_t u; } cv;
    cv.h2 = __float22bfloat162_rn(make_float2(a, b));
    return cv.u;
}
__device__ __forceinline__ float fast_tanh(float x) {
    float e = __expf(2.0f * x);
    return 1.0f - 2.0f * __builtin_amdgcn_rcpf(e + 1.0f);
}

// prep: W2,W3 (256x256 [k][n]) -> bf16 transposed Wt[n][k]; W4 (256x6) -> Wt4[16][256] padded
__global__ void prep_weights(const float* __restrict__ W2, const float* __restrict__ W3,
                             const float* __restrict__ W4,
                             ushort* __restrict__ Wt2, ushort* __restrict__ Wt3,
                             ushort* __restrict__ Wt4) {
    int idx = blockIdx.x * 256 + threadIdx.x;
    if (idx < 65536) {
        int k = idx >> 8, n = idx & 255;
        Wt2[n * 256 + k] = f2b(W2[k * 256 + n]);
        Wt3[n * 256 + k] = f2b(W3[k * 256 + n]);
    }
    if (idx < 4096) {
        int n = idx >> 8, k = idx & 255;
        Wt4[n * 256 + k] = (n < 6) ? f2b(W4[k * 6 + n]) : (ushort)0;
    }
}

// one L1 point: 2 adjacent neurons (jj0, jj0+1), packed uint writes
__device__ __forceinline__ void l1_point(ushort* __restrict__ Xd, const float* __restrict__ csb,
                                         int p, int jj0,
                                         float w0a, float w1a, float w2a, float ba,
                                         float w0b, float w1b, float w2b, float bb_) {
    float x = csb[p * 3], yc = csb[p * 3 + 1], tc = csb[p * 3 + 2];
    float pA = fmaf(x, w0a, fmaf(yc, w1a, fmaf(tc, w2a, ba)));
    float pB = fmaf(x, w0b, fmaf(yc, w1b, fmaf(tc, w2b, bb_)));
    float hA = fast_tanh(pA), hB = fast_tanh(pB);
    float dA = 1.0f - hA * hA, dB = 1.0f - hB * hB;
    *(uint32_t*)(&Xd[p * LDW + jj0])        = pk2(hA, hB);
    *(uint32_t*)(&Xd[(16 + p) * LDW + jj0]) = pk2(dA * w0a, dB * w0b);
    *(uint32_t*)(&Xd[(32 + p) * LDW + jj0]) = pk2(dA * w1a, dB * w1b);
    *(uint32_t*)(&Xd[(48 + p) * LDW + jj0]) = pk2(dA * w2a, dB * w2b);
}

// hidden layer: D = W(64x256 slice in regs) * src^T(256x64); epilogue -> dst (bf16)
// K-loop: nt-outer, rolling 3-deep B prefetch. Bias pre-loaded into C-in (nt=0).
__device__ __forceinline__ void dense_layer(const ushort* __restrict__ src,
                                            ushort* __restrict__ dst,
                                            const v8h (*wf)[8],
                                            const float* __restrict__ biasp,
                                            int wvg, int q, int l15) {
    v4f acc[4][4];
    #pragma unroll
    for (int a = 0; a < 4; a++) {
        // fwd stream (nt=0): C-in = bias (row = neuron); JVP streams: zero.
        acc[a][0] = *(const v4f*)(&biasp[wvg * 64 + a * 16 + q * 4]);
        #pragma unroll
        for (int b = 1; b < 4; b++) {
            v4f z = {0.0f, 0.0f, 0.0f, 0.0f};
            acc[a][b] = z;
        }
    }
    __builtin_amdgcn_s_setprio(1);
    #pragma unroll
    for (int nt = 0; nt < 4; nt++) {
        const ushort* cb = &src[(nt * 16 + l15) * LDW + q * 8];
        v8h B[3];
        B[0] = *(const v8h*)(cb);
        B[1] = *(const v8h*)(cb + 32);
        #pragma unroll
        for (int kk = 0; kk < 8; kk++) {
            if (kk < 6)
                B[(kk + 2) % 3] = *(const v8h*)(cb + (kk + 2) * 32);   // 2-ahead prefetch
            const v8h Bc = B[kk % 3];
            #pragma unroll
            for (int mt = 0; mt < 4; mt++)
                acc[mt][nt] = __builtin_amdgcn_mfma_f32_16x16x32_bf16(
                                  wf[mt][kk], Bc, acc[mt][nt], 0, 0, 0);
        }
    }
    __builtin_amdgcn_s_setprio(0);
    // D row(neuron) = mt*16 + q*4 + r, col = nt*16 + l15 (stream = nt, point = l15)
    #pragma unroll
    for (int mt = 0; mt < 4; mt++) {
        const int nb = wvg * 64 + mt * 16 + q * 4;
        float h0 = fast_tanh(acc[mt][0][0]);
        float h1 = fast_tanh(acc[mt][0][1]);
        float h2 = fast_tanh(acc[mt][0][2]);
        float h3 = fast_tanh(acc[mt][0][3]);
        float d0 = 1.0f - h0 * h0, d1 = 1.0f - h1 * h1;
        float d2 = 1.0f - h2 * h2, d3 = 1.0f - h3 * h3;
        uint2 w;
        w.x = pk2(h0, h1); w.y = pk2(h2, h3);
        *(uint2*)(&dst[l15 * LDW + nb]) = w;
        #pragma unroll
        for (int s = 1; s < 4; s++) {
            w.x = pk2(d0 * acc[mt][s][0], d1 * acc[mt][s][1]);
            w.y = pk2(d2 * acc[mt][s][2], d3 * acc[mt][s][3]);
            *(uint2*)(&dst[(s * 16 + l15) * LDW + nb]) = w;
        }
    }
}

__global__ __launch_bounds__(512, 2)
void mhd_fused(const float* __restrict__ coords,
               const float* __restrict__ W1, const float* __restrict__ b1,
               const float* __restrict__ b2, const float* __restrict__ b3,
               const float* __restrict__ b4,
               const float* __restrict__ wts,
               const ushort* __restrict__ Wt2, const ushort* __restrict__ Wt3,
               const ushort* __restrict__ Wt4,
               float* __restrict__ out, int npts, float inv_n) {
    __shared__ ushort XsA[64 * LDW];        // L1 out (single: barriers order reuse)
    __shared__ ushort XsB[2][64 * LDW];     // L2 out (dbuf: G2/G3 cross-over)
    __shared__ ushort XsC[64 * LDW];        // L3 out (single)
    __shared__ ushort W4s[16 * LDW];        // W4^T padded, bf16
    __shared__ float  bias_s[512];          // [0:256)=b2, [256:512)=b3
    __shared__ float  cs[2][TPTS * 3];      // coords (dbuf, 2 tiles ahead)
    __shared__ float  Y4[2][4][TPTS][8];    // [tile&1][stream][point][row]

    const int tid  = threadIdx.x;
    const int lane = tid & 63;
    const int wv   = tid >> 6;      // 0..7
    const int q    = lane >> 4;
    const int l15  = lane & 15;
    const int g3   = wv >> 2;       // 0 = G2 (L1+L2), 1 = G3 (L3+L4+residual+cs)
    const int wvg  = wv & 3;

    // ---- stage W4s + biases ---------------------------------------------------
    for (int idx = tid; idx < 16 * 256; idx += 512)
        W4s[(idx >> 8) * LDW + (idx & 255)] = Wt4[idx];
    bias_s[tid] = (tid < 256) ? b2[tid] : b3[tid - 256];

    // ---- weight fragments -> registers (group owns a layer, 64 neurons/wave) --
    const ushort* Wsrc = g3 ? Wt3 : Wt2;
    v8h wf[4][8];                                   // 128 regs
    #pragma unroll
    for (int mt = 0; mt < 4; mt++) {
        const int nrow = (wvg * 64 + mt * 16 + l15) * 256 + q * 8;
        #pragma unroll
        for (int kk = 0; kk < 8; kk++)
            wf[mt][kk] = *(const v8h*)(&Wsrc[nrow + kk * 32]);
    }

    // ---- L1 constants: G2 only (2 adjacent neurons / thread) ------------------
    const int jj0 = (tid & 127) * 2, half8 = (tid >> 7) * 8;
    float w0a = 0, w1a = 0, w2a = 0, ba = 0, w0b = 0, w1b = 0, w2b = 0, bb_ = 0;
    if (!g3) {
        w0a = W1[jj0];       w1a = W1[256 + jj0];     w2a = W1[512 + jj0];     ba  = b1[jj0];
        w0b = W1[jj0 + 1];   w1b = W1[256 + jj0 + 1]; w2b = W1[512 + jj0 + 1]; bb_ = b1[jj0 + 1];
    }

    const float b40 = b4[0], b41 = b4[1], b42 = b4[2], b43 = b4[3], b44 = b4[4], b45 = b4[5];
    const float wt0 = wts[0], wt1 = wts[1], wt2_ = wts[2], wt3_ = wts[3],
                wt4_ = wts[4], wt5 = wts[5], wt6 = wts[6];

    const int ntiles = (npts + TPTS - 1) / TPTS;
    const int nt_blk = (ntiles > (int)blockIdx.x)
                         ? (ntiles - (int)blockIdx.x + GRIDB - 1) / GRIDB : 0;
    float vsum = 0.0f;

    // ---- prologue: cs(0), cs(1); then L1(0) -> XsA ----------------------------
    if (tid < 96) {
        int b = tid / 48, r = tid % 48;
        if (b < nt_blk) {
            int p = r / 3, c = r % 3;
            int gp = ((int)blockIdx.x + b * GRIDB) * TPTS + p;
            if (gp >= npts) gp = npts - 1;
            cs[b][r] = coords[gp * 3 + c];
        }
    }
    __syncthreads();
    if (!g3 && nt_blk > 0) {
        #pragma unroll
        for (int pp = 0; pp < 8; pp++)
            l1_point(XsA, cs[0], half8 + pp, jj0, w0a, w1a, w2a, ba, w0b, w1b, w2b, bb_);
    }
    __syncthreads();

    // ---- main loop: 2 barriers per iteration ----------------------------------
    for (int i = 0; i <= nt_blk + 1; ++i) {
        // ================= P1: MFMA phase (both groups K-loop together) =========
        if (!g3) {
            if (i < nt_blk)
                dense_layer(XsA, XsB[i & 1], wf, bias_s, wvg, q, l15);         // L2(i)
        } else {
            if (i >= 1 && i <= nt_blk)
                dense_layer(XsB[(i + 1) & 1], XsC, wf, bias_s + 256, wvg, q, l15); // L3(i-1)
        }
        __syncthreads();   // B1: XsB(i)/XsC(i-1) ready; XsA free for L1(i+1)

        // ================= P2: L1 / L4 / residual / cs =================
        if (!g3) {
            if (i + 1 < nt_blk) {          // L1(tile i+1) -> XsA
                const float* csb = cs[(i + 1) & 1];
                #pragma unroll
                for (int pp = 0; pp < 8; pp++)
                    l1_point(XsA, csb, half8 + pp, jj0,
                             w0a, w1a, w2a, ba, w0b, w1b, w2b, bb_);
            }
        } else {
            // -- L4 (tile i-1): wave wvg handles stream wvg --
            if (i >= 1 && i <= nt_blk) {
                v4f a4 = {0.0f, 0.0f, 0.0f, 0.0f};
                __builtin_amdgcn_s_setprio(1);
                #pragma unroll
                for (int kk = 0; kk < 8; kk++) {
                    v8h A  = *(const v8h*)(&W4s[l15 * LDW + kk * 32 + q * 8]);
                    v8h Bf = *(const v8h*)(&XsC[(wvg * 16 + l15) * LDW + kk * 32 + q * 8]);
                    a4 = __builtin_amdgcn_mfma_f32_16x16x32_bf16(A, Bf, a4, 0, 0, 0);
                }
                __builtin_amdgcn_s_setprio(0);
                if (q < 2) {
                    #pragma unroll
                    for (int r = 0; r < 4; r++)
                        Y4[(i + 1) & 1][wvg][l15][q * 4 + r] = a4[r];   // (i-1)&1
                }
            }
            // -- residuals for tile i-2 (wave 4, lanes 0..15; pointer form) --
            if (wv == 4 && lane < 16 && i >= 2) {
                const int pb = ((int)blockIdx.x + (i - 2) * GRIDB) * TPTS;
                if (pb + lane < npts) {
                    const int ib = i & 1;   // (i-2)&1
                    const float* Yh = Y4[ib][0][lane];
                    const float* JX = Y4[ib][1][lane];
                    const float* JY = Y4[ib][2][lane];
                    const float* JT = Y4[ib][3][lane];
                    const float g1 = 1.5f;
                    float rho = Yh[0] + b40, vx = Yh[1] + b41, vy = Yh[2] + b42;
                    float Bx  = Yh[3] + b43, By = Yh[4] + b44, P  = Yh[5] + b45;
                    float v2 = vx * vx + vy * vy;
                    float dt_rho = JT[0];
                    float dt_rhovx = dt_rho * vx + rho * JT[1];
                    float dt_rhovy = dt_rho * vy + rho * JT[2];
                    auto dE = [&](const float* J) {
                        return J[5] * g1 + 0.5f * J[0] * v2 + rho * (vx * J[1] + vy * J[2]) + Bx * J[3] + By * J[4];
                    };
                    float dE_dx = dE(JX), dE_dy = dE(JY), dE_dt = dE(JT);
                    float div_v = JX[1] + JY[2];
                    float div_B = JX[3] + JY[4];
                    float continuity = dt_rho + rho * div_v;
                    float dPm_dx = JX[5] + Bx * JX[3] + By * JX[4];
                    float dPm_dy = JY[5] + Bx * JY[3] + By * JY[4];
                    float momentum_x = dt_rhovx + dPm_dx - (Bx * JX[3] + By * JY[3]);
                    float momentum_y = dt_rhovy + dPm_dy - (Bx * JX[4] + By * JY[4]);
                    auto dG = [&](const float* J) {
                        return J[1] * By + vx * J[4] - J[2] * Bx - vy * J[3];
                    };
                    float induction_x = JT[3] + dG(JY);
                    float induction_y = JT[4] - dG(JX);
                    float E = P * g1 + 0.5f * rho * v2 + 0.5f * (Bx * Bx + By * By);
                    float S = E + P + 0.5f * (Bx * Bx + By * By);
                    float dS_dx = dE_dx + JX[5] + Bx * JX[3] + By * JX[4];
                    float dS_dy = dE_dy + JY[5] + Bx * JY[3] + By * JY[4];
                    float D = Bx * vx + By * vy;
                    auto dD = [&](const float* J) {
                        return J[3] * vx + Bx * J[1] + J[4] * vy + By * J[2];
                    };
                    float dFx_dx = dS_dx * vx + S * JX[1] - dD(JX) * Bx - D * JX[3];
                    float dFy_dy = dS_dy * vy + S * JY[2] - dD(JY) * By - D * JY[4];
                    float energy = dE_dt + dFx_dx + dFy_dy;
                    vsum += wt0 * continuity * continuity
                          + wt1 * momentum_x * momentum_x
                          + wt2_ * momentum_y * momentum_y
                          + wt3_ * induction_x * induction_x
                          + wt4_ * induction_y * induction_y
                          + wt5 * energy * energy
                          + wt6 * div_B * div_B;
                }
            }
            // -- cs prefetch for tile i+2 (wave 7, lanes 0..47) --
            if (wv == 7 && lane < 48 && (i + 2) < nt_blk) {
                int p = lane / 3, c = lane % 3;
                int gp = ((int)blockIdx.x + (i + 2) * GRIDB) * TPTS + p;
                if (gp >= npts) gp = npts - 1;
                cs[i & 1][lane] = coords[gp * 3 + c];   // (i+2)&1 == i&1
            }
        }
        __syncthreads();   // B2: XsA(i+1), Y4(i-1), cs(i+2) ready
    }

    if (wv == 4) {
        #pragma unroll
        for (int off = 8; off >= 1; off >>= 1)
            vsum += __shfl_down(vsum, off, 64);
        if (lane == 0) atomicAdd(out, vsum * inv_n);
    }
}

extern "C" void kernel_launch(void* const* d_in, const int* in_sizes, int n_in,
                              void* d_out, int out_size, void* d_ws, size_t ws_size,
                              hipStream_t stream) {
    const float* coords = (const float*)d_in[0];
    const float* W1 = (const float*)d_in[1];
    const float* b1 = (const float*)d_in[2];
    const float* W2 = (const float*)d_in[3];
    const float* b2 = (const float*)d_in[4];
    const float* W3 = (const float*)d_in[5];
    const float* b3 = (const float*)d_in[6];
    const float* W4 = (const float*)d_in[7];
    const float* b4 = (const float*)d_in[8];
    const float* wts = (const float*)d_in[9];
    const int npts = in_sizes[0] / 3;

    ushort* Wt2 = (ushort*)d_ws;
    ushort* Wt3 = Wt2 + 65536;
    ushort* Wt4 = Wt3 + 65536;

    hipMemsetAsync(d_out, 0, sizeof(float), stream);
    prep_weights<<<256, 256, 0, stream>>>(W2, W3, W4, Wt2, Wt3, Wt4);
    mhd_fused<<<GRIDB, 512, 0, stream>>>(coords, W1, b1, b2, b3, b4, wts,
                                         Wt2, Wt3, Wt4, (float*)d_out, npts, 1.0f / npts);
}